// Round 1
// 93.593 us; speedup vs baseline: 1.0145x; 1.0145x over previous
//
#include <hip/hip_runtime.h>
#include <hip/hip_bf16.h>

// MOLELinear: out[n,o] = sum_i x[n,i] * (sum_e coef[b[n],e] * W[e,o,i]) + bias[o]
//
// R3 probe (disambiguate harness-fill floor vs hidden-slow-kernel):
//   - Timing model: dur_us (94.9) provably includes >=1 of the harness's
//     256 MiB workspace-poison fills (43.3 us each, 77% HBM peak) since both
//     our kernels are < 42.9 us (absent from top-5). Kernel roofline:
//     mole_main >= 8.2 us (51.6 MB intrinsic traffic), mix ~1.5 us.
//   - K1: unchanged (mix experts -> bf16 Wm in d_ws, 64 blocks, ~2 us).
//   - K2: unchanged grouped-GEMM structure (LDS-free, 64 atoms/block,
//     4 waves x 16x64 tile via mfma_f32_16x16x32_bf16), plus:
//       * __builtin_nontemporal_store for out (streaming write, never
//         re-read; keeps Wm/x resident in L2 instead of being evicted
//         by 25.6 MB of write allocate traffic)
//       * uniform bidx[t0]/bidx[t0+63] loads hoisted before per-lane
//         vector loads so the s-range scalar dependency issues earliest.

#define NE 16   // experts
#define NF 64   // in = out features

typedef __attribute__((ext_vector_type(8))) short  s16x8;   // 8 bf16 = 4 VGPR
typedef __attribute__((ext_vector_type(4))) float  f32x4;

// ---------------- Kernel 1: mix expert weights -> bf16 ----------------
// grid (16, 4) x 256 threads: blockIdx.x picks a 256-elem chunk of the 4096
// (o,i) positions; blockIdx.y picks 8 systems.
__global__ __launch_bounds__(256) void mix_weights_kernel(
    const float* __restrict__ coef,      // [S][NE]
    const float* __restrict__ W,         // [NE][4096]
    __hip_bfloat16* __restrict__ Wm)     // [S][4096]
{
    const int idx = (blockIdx.x << 8) + threadIdx.x;   // 0..4095
    const int s0  = blockIdx.y << 3;                   // 8 systems per block

    float w[NE];
#pragma unroll
    for (int e = 0; e < NE; ++e) w[e] = W[e * 4096 + idx];

#pragma unroll
    for (int si = 0; si < 8; ++si) {
        const int s = s0 + si;
        float acc = 0.f;
#pragma unroll
        for (int e = 0; e < NE; ++e) acc += coef[s * NE + e] * w[e];
        Wm[s * 4096 + idx] = __float2bfloat16(acc);
    }
}

__device__ __forceinline__ s16x8 cvt_bf16x8(const f32x4 a, const f32x4 b) {
    union { __hip_bfloat16 h[8]; s16x8 v; } u;
#pragma unroll
    for (int i = 0; i < 4; ++i) {
        u.h[i]     = __float2bfloat16(a[i]);
        u.h[4 + i] = __float2bfloat16(b[i]);
    }
    return u.v;
}

// ---------------- Kernel 2: grouped GEMM, LDS-free ----------------
__global__ __launch_bounds__(256) void mole_main(
    const float* __restrict__ x,            // [N][64]
    const int*   __restrict__ bidx,         // [N] sorted
    const __hip_bfloat16* __restrict__ Wm,  // [S][64][64]
    const float* __restrict__ bias,         // [64]
    float*       __restrict__ out,          // [N][64]
    int N)
{
    const int tid  = threadIdx.x;
    const int wv   = tid >> 6;              // wave 0..3 -> 16-atom subtile
    const int lane = tid & 63;
    const int mrow = lane & 15;             // m (A row) and n (B col) index
    const int quad = lane >> 4;             // k-subblock / C row group
    const int t0   = blockIdx.x << 6;       // first atom of block
    const int myrow = t0 + (wv << 4) + mrow;  // this lane's A-frag atom

    // systems spanned by this block (sorted indices -> contiguous range).
    // Uniform addresses -> scalar loads; issue before the vector loads so
    // the s-loop bound dependency resolves earliest.
    const int s0 = bidx[t0];
    const int s1 = bidx[min(t0 + 63, N - 1)];

    // ---- A fragments straight from global x (fp32 -> bf16 in regs)
    // A[m=mrow][k=quad*8+j] for k-step 0 (cols 0..31) and 1 (cols 32..63)
    f32x4 xa0, xa1, xb0, xb1;
    int row_sys;
    if (myrow < N) {
        const f32x4* p = (const f32x4*)(x + (size_t)myrow * NF);
        xa0 = p[quad * 2];
        xa1 = p[quad * 2 + 1];
        xb0 = p[8 + quad * 2];
        xb1 = p[8 + quad * 2 + 1];
        row_sys = bidx[myrow];
    } else {
        xa0 = xa1 = xb0 = xb1 = (f32x4){0.f, 0.f, 0.f, 0.f};
        row_sys = -1;
    }
    const s16x8 a0 = cvt_bf16x8(xa0, xa1);
    const s16x8 a1 = cvt_bf16x8(xb0, xb1);

    // acc[nt][r] = out[t0 + wv*16 + quad*4 + r][nt*16 + mrow]
    f32x4 acc[4];
#pragma unroll
    for (int nt = 0; nt < 4; ++nt) {
        const float bv = bias[nt * 16 + mrow];
        acc[nt] = (f32x4){bv, bv, bv, bv};
    }

    const s16x8 ZV = {0, 0, 0, 0, 0, 0, 0, 0};
    for (int s = s0; s <= s1; ++s) {
        const s16x8 am0 = (row_sys == s) ? a0 : ZV;
        const s16x8 am1 = (row_sys == s) ? a1 : ZV;
        const __hip_bfloat16* wp = Wm + ((size_t)s << 12);
#pragma unroll
        for (int nt = 0; nt < 4; ++nt) {
            // B[k=quad*8+j][n=mrow] = Wm[s][o=nt*16+mrow][k]
            const s16x8 b0 = *(const s16x8*)(wp + (nt * 16 + mrow) * NF + quad * 8);
            const s16x8 b1 = *(const s16x8*)(wp + (nt * 16 + mrow) * NF + 32 + quad * 8);
            acc[nt] = __builtin_amdgcn_mfma_f32_16x16x32_bf16(am0, b0, acc[nt], 0, 0, 0);
            acc[nt] = __builtin_amdgcn_mfma_f32_16x16x32_bf16(am1, b1, acc[nt], 0, 0, 0);
        }
    }

    // Epilogue: C/D layout col(n)=lane&15, row(m)=quad*4+reg.
    // Non-temporal: out is write-once, never re-read -> don't let 25.6 MB of
    // streaming writes evict Wm / x lines from L2.
#pragma unroll
    for (int nt = 0; nt < 4; ++nt) {
#pragma unroll
        for (int r = 0; r < 4; ++r) {
            const int arow = t0 + (wv << 4) + (quad << 2) + r;
            if (arow < N)
                __builtin_nontemporal_store(acc[nt][r],
                    out + (size_t)arow * NF + nt * 16 + mrow);
        }
    }
}

extern "C" void kernel_launch(void* const* d_in, const int* in_sizes, int n_in,
                              void* d_out, int out_size, void* d_ws, size_t ws_size,
                              hipStream_t stream) {
    const float* x    = (const float*)d_in[0];
    const float* coef = (const float*)d_in[1];
    const int*   bidx = (const int*)d_in[2];
    const float* W    = (const float*)d_in[3];
    const float* bias = (const float*)d_in[4];
    float* out = (float*)d_out;

    const int N = in_sizes[2];            // number of atoms (100000)

    __hip_bfloat16* Wm = (__hip_bfloat16*)d_ws;   // [32][64][64] bf16 = 256 KB

    mix_weights_kernel<<<dim3(16, 4), 256, 0, stream>>>(coef, W, Wm);

    const int nblocks = (N + 63) / 64;
    mole_main<<<nblocks, 256, 0, stream>>>(x, bidx, Wm, bias, out, N);
}